// Round 1
// baseline (423.473 us; speedup 1.0000x reference)
//
#include <hip/hip_runtime.h>

#define CELLS 81
#define ND 9
#define HID 100

__global__ __launch_bounds__(256) void sudoku_kernel(
    const float* __restrict__ x_all,
    const float* __restrict__ W1,
    const float* __restrict__ W2,
    float* __restrict__ out,
    int nBoards)
{
    const int board = blockIdx.x;
    const int tid = threadIdx.x;
    const float* x = x_all + (size_t)board * (CELLS * ND);

    __shared__ float sW1[HID * 27];       // 10800 B
    __shared__ float sW2[ND * HID];       // 3600 B
    __shared__ float hbuf[CELLS * HID];   // 32400 B
    __shared__ float ybuf[CELLS * ND];    // 2916 B
    __shared__ float xp[CELLS * ND];      // 2916 B
    __shared__ float cnt[3 * 81];         // row/col/box digit counts
    __shared__ int   digit[CELLS];
    __shared__ int   lst[CELLS];          // compacted empty-cell list
    __shared__ int   lpos[CELLS];         // cell -> position in lst
    __shared__ float scoreV[CELLS];
    __shared__ int   scoreD[CELLS];
    __shared__ int   scoreQ[CELLS];
    __shared__ int   nEmptyS;

    // ---- init ----
    for (int i = tid; i < HID * 27; i += 256) sW1[i] = W1[i];
    for (int i = tid; i < ND * HID; i += 256) sW2[i] = W2[i];
    for (int i = tid; i < CELLS * ND; i += 256) xp[i] = x[i];
    for (int i = tid; i < 243; i += 256) cnt[i] = 0.f;
    if (tid == 0) nEmptyS = 0;
    __syncthreads();

    if (tid < CELLS) {
        int q = tid;
        int dig = -1;
        for (int d = 0; d < ND; ++d) {
            if (x[q * ND + d] > 0.5f) { dig = d; break; }
        }
        digit[q] = dig;
        if (dig < 0) {
            int p = atomicAdd(&nEmptyS, 1);
            lst[p] = q;
            lpos[q] = p;
        } else {
            int r = q / 9, c = q - r * 9, bx = (r / 3) * 3 + (c / 3);
            atomicAdd(&cnt[r * 9 + dig], 1.0f);
            atomicAdd(&cnt[81 + c * 9 + dig], 1.0f);
            atomicAdd(&cnt[162 + bx * 9 + dig], 1.0f);
        }
    }

    // ---- solve loop (per-board length = its own empty count; extra
    //      reference iterations are no-ops, so this matches the scan) ----
    for (;;) {
        __syncthreads();
        const int ne = nEmptyS;
        if (ne == 0) break;

        // Phase A: hidden layer, thread per (empty cell, hidden unit)
        for (int i = tid; i < ne * HID; i += 256) {
            int qi = i / HID;
            int u  = i - qi * HID;
            int q  = lst[qi];
            int r = q / 9, c = q - r * 9, bx = (r / 3) * 3 + (c / 3);
            const float* w  = &sW1[u * 27];
            const float* cr = &cnt[r * 9];
            const float* cc = &cnt[81 + c * 9];
            const float* cb = &cnt[162 + bx * 9];
            float a0 = 0.f, a1 = 0.f, a2 = 0.f;
#pragma unroll
            for (int d = 0; d < 9; ++d) {
                a0 += cr[d] * w[d];
                a1 += cc[d] * w[9 + d];
                a2 += cb[d] * w[18 + d];
            }
            float h = a0 + a1 + a2;
            hbuf[qi * HID + u] = h > 0.f ? h : 0.f;
        }
        __syncthreads();

        // Phase B: output logits, thread per (empty cell, digit)
        for (int i = tid; i < ne * ND; i += 256) {
            int qi = i / ND;
            int d  = i - qi * ND;
            const float* hp = &hbuf[qi * HID];
            const float* wp = &sW2[d * HID];
            float a0 = 0.f, a1 = 0.f;
#pragma unroll 5
            for (int u = 0; u < 50; ++u) {
                a0 += hp[u] * wp[u];
                a1 += hp[50 + u] * wp[50 + u];
            }
            ybuf[i] = a0 + a1;
        }
        __syncthreads();

        // Phase C: softmax + per-cell best digit (first-max semantics)
        if (tid < ne) {
            int qi = tid;
            int q  = lst[qi];
            float y[9];
            float m = -1e30f;
#pragma unroll
            for (int d = 0; d < 9; ++d) {
                y[d] = ybuf[qi * ND + d];
                m = fmaxf(m, y[d]);
            }
            float e[9];
            float sum = 0.f;
#pragma unroll
            for (int d = 0; d < 9; ++d) {
                e[d] = expf(y[d] - m);
                sum += e[d];
            }
            float bv = -1.f;
            int bd = 0;
#pragma unroll
            for (int d = 0; d < 9; ++d) {
                float s = e[d] / sum;
                xp[q * ND + d] = s;
                if (s > bv) { bv = s; bd = d; }   // strict > : first max wins
            }
            scoreV[qi] = bv;
            scoreD[qi] = bd;
            scoreQ[qi] = q;
        }
        __syncthreads();

        // Phase D: argmax over cells (ties -> smallest q, matching jnp.argmax)
        if (tid < 64) {
            float v = -1.f;
            int q = 1 << 20;
            int dd = 0;
            for (int i = tid; i < ne; i += 64) {
                float sv = scoreV[i];
                int   sq = scoreQ[i];
                if (sv > v || (sv == v && sq < q)) { v = sv; q = sq; dd = scoreD[i]; }
            }
#pragma unroll
            for (int off = 32; off >= 1; off >>= 1) {
                float ov = __shfl_xor(v, off);
                int   oq = __shfl_xor(q, off);
                int   od = __shfl_xor(dd, off);
                if (ov > v || (ov == v && oq < q)) { v = ov; q = oq; dd = od; }
            }
            if (tid == 0) {
                // Phase E: fill chosen cell, update counts, swap-remove from list
                digit[q] = dd;
                int r = q / 9, c = q - r * 9, bx = (r / 3) * 3 + (c / 3);
                cnt[r * 9 + dd]        += 1.0f;
                cnt[81 + c * 9 + dd]   += 1.0f;
                cnt[162 + bx * 9 + dd] += 1.0f;
                int p = lpos[q];
                int last = lst[ne - 1];
                lst[p] = last;
                lpos[last] = p;
                nEmptyS = ne - 1;
            }
        }
    }

    // ---- outputs: x_pred then x_final, each (B,81,9) flat ----
    float* po = out + (size_t)board * (CELLS * ND);
    float* fo = out + (size_t)nBoards * (CELLS * ND) + (size_t)board * (CELLS * ND);
    for (int i = tid; i < CELLS * ND; i += 256) {
        po[i] = xp[i];
        int q = i / ND, d = i - q * ND;
        fo[i] = (digit[q] == d) ? 1.0f : 0.0f;
    }
}

extern "C" void kernel_launch(void* const* d_in, const int* in_sizes, int n_in,
                              void* d_out, int out_size, void* d_ws, size_t ws_size,
                              hipStream_t stream) {
    const float* x  = (const float*)d_in[0];
    // d_in[1] is the constraint mask c — structurally known, not needed.
    const float* W1 = (const float*)d_in[2];
    const float* W2 = (const float*)d_in[3];
    float* out = (float*)d_out;
    int nBoards = in_sizes[0] / (CELLS * ND);
    sudoku_kernel<<<nBoards, 256, 0, stream>>>(x, W1, W2, out, nBoards);
}

// Round 2
// 249.870 us; speedup vs baseline: 1.6948x; 1.6948x over previous
//
#include <hip/hip_runtime.h>

#define CELLS 81
#define ND 9
#define HID 100

__global__ __launch_bounds__(256) void sudoku_kernel(
    const float* __restrict__ x_all,
    const float* __restrict__ W1,
    const float* __restrict__ W2,
    float* __restrict__ out,
    int nBoards)
{
    const int board = blockIdx.x;
    const int tid = threadIdx.x;
    const float* x = x_all + (size_t)board * (CELLS * ND);
    float* po = out + (size_t)board * (CELLS * ND);
    float* fo = out + (size_t)nBoards * (CELLS * ND) + (size_t)board * (CELLS * ND);

    // LDS budget (4 blocks/CU needs <= 40960 B): total = 38948 B
    __shared__ float z[CELLS * HID];     // 32400 pre-activations (empty cells only)
    __shared__ float sW2[ND * HID];      // 3600
    __shared__ float cnt[3 * 81];        // 972, used for init only
    __shared__ int   digit[CELLS];       // 324
    __shared__ int   lst[CELLS];         // 324 compacted empty list
    __shared__ int   lpos[CELLS];        // 324 cell -> list pos
    __shared__ float scoreV[CELLS];      // 324 cached best softmax per cell
    __shared__ int   scoreD[CELLS];      // 324 cached best digit per cell
    __shared__ int   chlist[CELLS];      // 324 changed-cell list
    __shared__ int   nEmptyS, nChS, pChS, dChS;

    // ---- init ----
    for (int i = tid; i < ND * HID; i += 256) sW2[i] = W2[i];
    for (int i = tid; i < 243; i += 256) cnt[i] = 0.f;
    for (int i = tid; i < CELLS * ND; i += 256) po[i] = x[i];
    if (tid == 0) { nEmptyS = 0; nChS = 0; pChS = -1; dChS = 0; }
    __syncthreads();

    if (tid < CELLS) {
        int q = tid, dig = -1;
        #pragma unroll
        for (int d = 0; d < ND; ++d)
            if (x[q * ND + d] > 0.5f) { dig = d; break; }
        digit[q] = dig;
        if (dig < 0) {
            int p = atomicAdd(&nEmptyS, 1);
            lst[p] = q; lpos[q] = p;
        } else {
            int r = q / 9, c = q - r * 9, bx = (r / 3) * 3 + (c / 3);
            atomicAdd(&cnt[r * 9 + dig], 1.f);
            atomicAdd(&cnt[81 + c * 9 + dig], 1.f);
            atomicAdd(&cnt[162 + bx * 9 + dig], 1.f);
        }
    }
    __syncthreads();

    // ---- solve loop: one placement per iteration ----
    for (;;) {
        const int ne = nEmptyS;
        if (ne == 0) break;
        const int pC = pChS, dC = dChS;
        int pr = 0, pc = 0, pb = 0;
        if (pC >= 0) { pr = pC / 9; pc = pC - pr * 9; pb = (pr / 3) * 3 + pc / 3; }

        // Phase U: incremental z update (or full init on first pass) + changed list
        if (pC < 0) {
            for (int i = tid; i < ne * HID; i += 256) {
                int qi = i / HID, u = i - qi * HID;
                int q = lst[qi];
                int r = q / 9, c = q - r * 9, bx = (r / 3) * 3 + c / 3;
                const float* w  = &W1[u * 27];
                const float* cr = &cnt[r * 9];
                const float* cc = &cnt[81 + c * 9];
                const float* cb = &cnt[162 + bx * 9];
                float a0 = 0.f, a1 = 0.f, a2 = 0.f;
                #pragma unroll
                for (int d = 0; d < 9; ++d) {
                    a0 += cr[d] * w[d];
                    a1 += cc[d] * w[9 + d];
                    a2 += cb[d] * w[18 + d];
                }
                z[q * HID + u] = a0 + a1 + a2;
                if (u == 0) { int t = atomicAdd(&nChS, 1); chlist[t] = q; }
            }
        } else {
            for (int i = tid; i < ne * HID; i += 256) {
                int qi = i / HID, u = i - qi * HID;
                int q = lst[qi];
                int r = q / 9, c = q - r * 9, bx = (r / 3) * 3 + c / 3;
                bool mr = (r == pr), mc = (c == pc), mb = (bx == pb);
                if (mr | mc | mb) {
                    float dz = 0.f;
                    const float* w = &W1[u * 27 + dC];
                    if (mr) dz += w[0];
                    if (mc) dz += w[9];
                    if (mb) dz += w[18];
                    z[q * HID + u] += dz;
                    if (u == 0) { int t = atomicAdd(&nChS, 1); chlist[t] = q; }
                }
            }
        }
        __syncthreads();
        const int nch = nChS;

        // Phase B+C fused: 16 lanes per changed cell -> logits, softmax,
        // xp write, per-cell best digit (first-max semantics)
        for (int i = tid; i < nch * 16; i += 256) {
            int ci = i >> 4, ln = i & 15;
            int q = chlist[ci];
            int d = ln < 9 ? ln : 8;
            const float4* zp = (const float4*)&z[q * HID];
            const float4* wp = (const float4*)&sW2[d * HID];
            float acc = 0.f;
            #pragma unroll
            for (int u = 0; u < 25; ++u) {
                float4 zv = zp[u], wv = wp[u];
                acc += fmaxf(zv.x, 0.f) * wv.x;
                acc += fmaxf(zv.y, 0.f) * wv.y;
                acc += fmaxf(zv.z, 0.f) * wv.z;
                acc += fmaxf(zv.w, 0.f) * wv.w;
            }
            float y = (ln < 9) ? acc : -1e30f;
            float m = y;
            #pragma unroll
            for (int off = 8; off >= 1; off >>= 1)
                m = fmaxf(m, __shfl_xor(m, off, 16));
            float e = (ln < 9) ? expf(y - m) : 0.f;
            float s = e;
            #pragma unroll
            for (int off = 8; off >= 1; off >>= 1)
                s += __shfl_xor(s, off, 16);
            float p = e / s;
            if (ln < 9) po[q * ND + ln] = p;
            float bv = (ln < 9) ? p : -1.f;
            int   bd = (ln < 9) ? ln : 99;
            #pragma unroll
            for (int off = 8; off >= 1; off >>= 1) {
                float ov = __shfl_xor(bv, off, 16);
                int   od = __shfl_xor(bd, off, 16);
                if (ov > bv || (ov == bv && od < bd)) { bv = ov; bd = od; }
            }
            if (ln == 0) { scoreV[q] = bv; scoreD[q] = bd; }
        }
        __syncthreads();

        // Phase D: global argmax over empty cells (ties -> smallest cell id)
        if (tid < 64) {
            float v = -1.f; int qb = 1 << 20, db = 0;
            for (int i = tid; i < ne; i += 64) {
                int q = lst[i];
                float sv = scoreV[q];
                if (sv > v || (sv == v && q < qb)) { v = sv; qb = q; db = scoreD[q]; }
            }
            #pragma unroll
            for (int off = 32; off >= 1; off >>= 1) {
                float ov = __shfl_xor(v, off);
                int   oq = __shfl_xor(qb, off);
                int   od = __shfl_xor(db, off);
                if (ov > v || (ov == v && oq < qb)) { v = ov; qb = oq; db = od; }
            }
            if (tid == 0) {
                digit[qb] = db;
                int p = lpos[qb], last = lst[ne - 1];
                lst[p] = last; lpos[last] = p;
                nEmptyS = ne - 1;
                pChS = qb; dChS = db; nChS = 0;
            }
        }
        __syncthreads();
    }

    // ---- x_final ----
    for (int i = tid; i < CELLS * ND; i += 256) {
        int q = i / ND, d = i - q * ND;
        fo[i] = (digit[q] == d) ? 1.0f : 0.0f;
    }
}

extern "C" void kernel_launch(void* const* d_in, const int* in_sizes, int n_in,
                              void* d_out, int out_size, void* d_ws, size_t ws_size,
                              hipStream_t stream) {
    const float* x  = (const float*)d_in[0];
    // d_in[1] is the constraint mask c — structurally known, not needed.
    const float* W1 = (const float*)d_in[2];
    const float* W2 = (const float*)d_in[3];
    float* out = (float*)d_out;
    int nBoards = in_sizes[0] / (CELLS * ND);
    sudoku_kernel<<<nBoards, 256, 0, stream>>>(x, W1, W2, out, nBoards);
}

// Round 3
// 160.981 us; speedup vs baseline: 2.6306x; 1.5522x over previous
//
#include <hip/hip_runtime.h>

#define CELLS 81
#define ND 9
#define HID 100

__global__ __launch_bounds__(256, 4) void sudoku_kernel(
    const float* __restrict__ x_all,
    const float* __restrict__ W1,
    const float* __restrict__ W2,
    float* __restrict__ out,
    int nBoards)
{
    const int board = blockIdx.x;
    const int tid = threadIdx.x;
    const int l = tid & 31;
    const float* x = x_all + (size_t)board * (CELLS * ND);
    float* po = out + (size_t)board * (CELLS * ND);
    float* fo = out + (size_t)nBoards * (CELLS * ND) + (size_t)board * (CELLS * ND);

    __shared__ float z[CELLS * HID];     // 32400 B  pre-activations
    __shared__ float cnt[3 * 81];        // init only
    __shared__ int   digit[CELLS];
    __shared__ int   lst[CELLS];         // compacted empty list
    __shared__ int   lpos[CELLS];
    __shared__ float scoreV[CELLS];      // cached best softmax per cell
    __shared__ int   scoreD[CELLS];
    __shared__ int   chlist[CELLS];      // q | mask<<8
    __shared__ int   nEmptyS, nChS, pChS, dChS;

    // ---- W2 column slice in registers: lane l owns u = l+32k ----
    float w2r[4][9];
    #pragma unroll
    for (int k = 0; k < 4; ++k) {
        int u = l + 32 * k;
        #pragma unroll
        for (int d = 0; d < 9; ++d)
            w2r[k][d] = (u < HID) ? W2[d * HID + u] : 0.f;
    }

    // ---- init ----
    for (int i = tid; i < 243; i += 256) cnt[i] = 0.f;
    for (int i = tid; i < CELLS * ND; i += 256) po[i] = x[i];
    if (tid == 0) { nEmptyS = 0; nChS = 0; pChS = -1; dChS = 0; }
    __syncthreads();

    if (tid < CELLS) {
        int q = tid, dig = -1;
        #pragma unroll
        for (int d = 0; d < ND; ++d)
            if (x[q * ND + d] > 0.5f) { dig = d; break; }
        digit[q] = dig;
        if (dig < 0) {
            int p = atomicAdd(&nEmptyS, 1);
            lst[p] = q; lpos[q] = p;
        } else {
            int r = q / 9, c = q - r * 9, bx = (r / 3) * 3 + (c / 3);
            atomicAdd(&cnt[r * 9 + dig], 1.f);
            atomicAdd(&cnt[81 + c * 9 + dig], 1.f);
            atomicAdd(&cnt[162 + bx * 9 + dig], 1.f);
        }
    }

    // ---- solve loop ----
    for (;;) {
        __syncthreads();                      // placement + nChS reset visible
        const int ne = nEmptyS;
        if (ne == 0) break;
        const int pC = pChS, dC = dChS;

        if (pC < 0) {
            // first pass: full z init, all empty cells are "changed"
            for (int i = tid; i < ne * HID; i += 256) {
                int qi = i / HID, u = i - qi * HID;
                int q = lst[qi];
                int r = q / 9, c = q - r * 9, bx = (r / 3) * 3 + c / 3;
                const float* w  = &W1[u * 27];
                const float* cr = &cnt[r * 9];
                const float* cc = &cnt[81 + c * 9];
                const float* cb = &cnt[162 + bx * 9];
                float a0 = 0.f, a1 = 0.f, a2 = 0.f;
                #pragma unroll
                for (int d = 0; d < 9; ++d) {
                    a0 += cr[d] * w[d];
                    a1 += cc[d] * w[9 + d];
                    a2 += cb[d] * w[18 + d];
                }
                z[q * HID + u] = a0 + a1 + a2;
            }
            if (tid < ne) chlist[tid] = lst[tid];
            if (tid == 0) nChS = ne;
        } else {
            const int pr = pC / 9, pc = pC - pr * 9, pb = (pr / 3) * 3 + pc / 3;
            // U1: build changed list with packed mask
            if (tid < ne) {
                int q = lst[tid];
                int r = q / 9, c = q - r * 9, bx = (r / 3) * 3 + c / 3;
                int m = (r == pr ? 1 : 0) | (c == pc ? 2 : 0) | (bx == pb ? 4 : 0);
                if (m) { int t = atomicAdd(&nChS, 1); chlist[t] = q | (m << 8); }
            }
            __syncthreads();
            // U2: apply W1-column delta to z of changed cells
            const int nch = nChS;
            for (int i = tid; i < nch * HID; i += 256) {
                int ci = i / HID, u = i - ci * HID;
                int e = chlist[ci];
                int q = e & 255, m = e >> 8;
                const float* w = &W1[u * 27 + dC];
                float dz = 0.f;
                if (m & 1) dz += w[0];
                if (m & 2) dz += w[9];
                if (m & 4) dz += w[18];
                z[q * HID + u] += dz;
            }
        }
        __syncthreads();

        // B/C: 32 lanes per changed cell -> logits, softmax, po, best digit
        const int nch = nChS;
        for (int i = tid; i < nch * 32; i += 256) {
            int ci = i >> 5;
            int q = chlist[ci] & 255;
            float acc[9] = {0.f,0.f,0.f,0.f,0.f,0.f,0.f,0.f,0.f};
            #pragma unroll
            for (int k = 0; k < 4; ++k) {
                int u = l + 32 * k;
                float zv = z[q * HID + (u < HID ? u : HID - 1)];
                zv = fmaxf(zv, 0.f);
                #pragma unroll
                for (int d = 0; d < 9; ++d) acc[d] += zv * w2r[k][d];
            }
            #pragma unroll
            for (int off = 16; off >= 1; off >>= 1) {
                #pragma unroll
                for (int d = 0; d < 9; ++d)
                    acc[d] += __shfl_xor(acc[d], off, 32);
            }
            // every lane now holds all 9 logits: redundant softmax + argmax
            float m9 = acc[0];
            #pragma unroll
            for (int d = 1; d < 9; ++d) m9 = fmaxf(m9, acc[d]);
            float s = 0.f;
            #pragma unroll
            for (int d = 0; d < 9; ++d) { acc[d] = expf(acc[d] - m9); s += acc[d]; }
            float inv = 1.f / s;
            float bv = -1.f; int bd = 0;
            #pragma unroll
            for (int d = 0; d < 9; ++d) {
                float p = acc[d] * inv;
                acc[d] = p;
                if (p > bv) { bv = p; bd = d; }  // strict >: first max wins
            }
            if (l < 9) po[q * ND + l] = acc[l];
            if (l == 0) { scoreV[q] = bv; scoreD[q] = bd; }
        }
        __syncthreads();

        // D: global argmax over empty cells (ties -> smallest cell id)
        if (tid < 64) {
            float v = -1.f; int qb = 1 << 20, db = 0;
            for (int i = tid; i < ne; i += 64) {
                int q = lst[i];
                float sv = scoreV[q];
                if (sv > v || (sv == v && q < qb)) { v = sv; qb = q; db = scoreD[q]; }
            }
            #pragma unroll
            for (int off = 32; off >= 1; off >>= 1) {
                float ov = __shfl_xor(v, off);
                int   oq = __shfl_xor(qb, off);
                int   od = __shfl_xor(db, off);
                if (ov > v || (ov == v && oq < qb)) { v = ov; qb = oq; db = od; }
            }
            if (tid == 0) {
                digit[qb] = db;
                int p = lpos[qb], last = lst[ne - 1];
                lst[p] = last; lpos[last] = p;
                nEmptyS = ne - 1;
                pChS = qb; dChS = db; nChS = 0;
            }
        }
    }

    // ---- x_final ----
    for (int i = tid; i < CELLS * ND; i += 256) {
        int q = i / ND, d = i - q * ND;
        fo[i] = (digit[q] == d) ? 1.0f : 0.0f;
    }
}

extern "C" void kernel_launch(void* const* d_in, const int* in_sizes, int n_in,
                              void* d_out, int out_size, void* d_ws, size_t ws_size,
                              hipStream_t stream) {
    const float* x  = (const float*)d_in[0];
    // d_in[1] is the constraint mask c — structurally known, not needed.
    const float* W1 = (const float*)d_in[2];
    const float* W2 = (const float*)d_in[3];
    float* out = (float*)d_out;
    int nBoards = in_sizes[0] / (CELLS * ND);
    sudoku_kernel<<<nBoards, 256, 0, stream>>>(x, W1, W2, out, nBoards);
}